// Round 1
// baseline (491.491 us; speedup 1.0000x reference)
//
#include <hip/hip_runtime.h>

#define B_  2
#define S_  2048
#define D_  2048
#define H_  16
#define HD_ 128

typedef __bf16 bf16;
typedef __bf16 bf16x4 __attribute__((ext_vector_type(4)));
typedef __bf16 bf16x8 __attribute__((ext_vector_type(8)));
typedef float  f32x4  __attribute__((ext_vector_type(4)));

// async global->LDS 16B copy: lds dst = wave-uniform base + lane*16
__device__ __forceinline__ void gld_lds16(const void* g, void* l) {
    __builtin_amdgcn_global_load_lds(
        (const __attribute__((address_space(1))) unsigned int*)g,
        (__attribute__((address_space(3))) unsigned int*)l, 16, 0, 0);
}

__device__ __forceinline__ f32x4 mfma16(bf16x8 a, bf16x8 b, f32x4 c) {
    return __builtin_amdgcn_mfma_f32_16x16x32_bf16(a, b, c, 0, 0, 0);
}

// raw barrier + compiler memory fence (prevents ds_read hoisting above it)
#define BAR()        do { __builtin_amdgcn_s_barrier(); asm volatile("" ::: "memory"); } while (0)
// rule-18: sched_barrier(0) right after lgkmcnt(0) so MFMAs can't hoist past the wait
#define WAIT_LGKM0() do { asm volatile("s_waitcnt lgkmcnt(0)" ::: "memory"); \
                          __builtin_amdgcn_sched_barrier(0); } while (0)

// ---------------- precast: x f32 -> hi/lo bf16 planes ----------------
__global__ __launch_bounds__(256)
void precast_kernel(const float* __restrict__ x, bf16* __restrict__ xh,
                    bf16* __restrict__ xl) {
    int i = (blockIdx.x * 256 + threadIdx.x) * 8;
    float4 a = *(const float4*)(x + i);
    float4 b = *(const float4*)(x + i + 4);
    float av[8] = {a.x, a.y, a.z, a.w, b.x, b.y, b.z, b.w};
    bf16x8 h8, l8;
#pragma unroll
    for (int e = 0; e < 8; e++) {
        bf16 hv = (bf16)av[e];
        h8[e] = hv;
        l8[e] = (bf16)(av[e] - (float)hv);
    }
    *(bf16x8*)(xh + i) = h8;
    *(bf16x8*)(xl + i) = l8;
}

// ---------------- precast masks: f32 * sw -> bf16 ----------------
// grid 2048: src0 only. grid 4096: src0 then src1.
__global__ __launch_bounds__(256)
void precast_mask(const float* __restrict__ s0, bf16* __restrict__ d0,
                  const float* __restrict__ s1, bf16* __restrict__ d1,
                  const float* __restrict__ swp) {
    const float sw = swp[0];
    int bid = blockIdx.x;
    const float* src = s0; bf16* dst = d0;
    if (bid >= 2048) { src = s1; dst = d1; bid -= 2048; }
    int i = (bid * 256 + threadIdx.x) * 8;
    float4 a = *(const float4*)(src + i);
    float4 b = *(const float4*)(src + i + 4);
    bf16x8 o;
    o[0] = (bf16)(a.x * sw); o[1] = (bf16)(a.y * sw);
    o[2] = (bf16)(a.z * sw); o[3] = (bf16)(a.w * sw);
    o[4] = (bf16)(b.x * sw); o[5] = (bf16)(b.y * sw);
    o[6] = (bf16)(b.z * sw); o[7] = (bf16)(b.w * sw);
    *(bf16x8*)(dst + i) = o;
}

// =================== 8-phase double-buffered GEMM ===================
// C[m,n] = sum_k A[m,k] * B[n,k]; A,B bf16 staged via global_load_lds with
// XOR column swizzle; counted vmcnt (never 0 mid-loop); per-K-tile 4-phase
// quadrant schedule with setprio around MFMA clusters.
// MODE 0: q/k projection. Virtual K = 4096 (xh tiles 0..31, xl 32..63), B wraps.
//         Epilogue: *hm, hi/lo split scatter into qh/ql (n0<2048) or kh/kl.
// MODE 1: v projection (hi plane only, K=2048). Epilogue: *hm, LDS transpose,
//         write V^T [bh][d][s] directly (replaces separate transpose kernel).
// MODE 2: output projection, f32 epilogue.
template<int BM, int BN, int WM, int WN, int MODE>
__global__ __launch_bounds__(512)
void gemm8p(const bf16* __restrict__ Ah_g, const bf16* __restrict__ Al_g,
            const bf16* __restrict__ Bq, const bf16* __restrict__ Bk,
            const float* __restrict__ hm,
            bf16* __restrict__ o_qh, bf16* __restrict__ o_ql,
            bf16* __restrict__ o_kh, bf16* __restrict__ o_kl,
            bf16* __restrict__ o_vt, float* __restrict__ o_f32,
            int nt) {
    constexpr int IM = BM / WM / 16;        // M-fragments per wave
    constexpr int JN = BN / WN / 16;        // N-fragments per wave
    constexpr int IH = IM / 2, JH = JN / 2; // quadrant halves
    constexpr int ISSA = BM / 64;           // gld_lds issues per wave for A tile
    constexpr int ISSB = BN / 64;
    constexpr int VMW = ISSA + ISSB;        // issues per wave per K-tile
    constexpr int BUFE = (BM + BN) * 64;    // bf16 elems per buffer

    __shared__ bf16 sm[2 * BUFE];

    const int t = threadIdx.x;
    const int wave = t >> 6, lane = t & 63;
    const int lrow = lane & 15, quad = lane >> 4;
    const int wr = wave / WN, wc = wave % WN;
    const int m0 = blockIdx.y * BM, n0 = blockIdx.x * BN;

    const int nsec = (MODE == 0) ? (n0 & (D_ - 1)) : n0;
    const bf16* Bg = (MODE == 0 && n0 >= D_) ? Bk : Bq;

    const int arow = wr * (BM / WM) + lrow;
    const int brow = wc * (BN / WN) + lrow;
    const int g0e = (quad ^ (lrow & 7)) * 8;   // swizzled group, kk=0
    const int g1e = g0e ^ 32;                  // kk=1

    auto stage_A = [&](int kt, int p) {
        const bf16* As = (MODE == 0 && kt >= 32) ? Al_g : Ah_g;
        const int kc = ((MODE == 0) ? (kt & 31) : kt) * 64;
        bf16* buf = sm + p * BUFE;
        const int r0 = wave * (BM / 8);
#pragma unroll
        for (int pp = 0; pp < ISSA; pp++) {
            int r = r0 + pp * 8 + (lane >> 3);
            int gc = ((lane & 7) ^ (r & 7)) * 8;   // pre-swizzled source col
            gld_lds16(As + (size_t)(m0 + r) * D_ + kc + gc,
                      buf + (r0 + pp * 8) * 64);
        }
    };
    auto stage_B = [&](int kt, int p) {
        const int kc = ((MODE == 0) ? (kt & 31) : kt) * 64;
        bf16* buf = sm + p * BUFE + BM * 64;
        const int r0 = wave * (BN / 8);
#pragma unroll
        for (int pp = 0; pp < ISSB; pp++) {
            int r = r0 + pp * 8 + (lane >> 3);
            int gc = ((lane & 7) ^ (r & 7)) * 8;
            gld_lds16(Bg + (size_t)(nsec + r) * D_ + kc + gc,
                      buf + (r0 + pp * 8) * 64);
        }
    };

    f32x4 acc[IM][JN];
#pragma unroll
    for (int i = 0; i < IM; i++)
#pragma unroll
        for (int j = 0; j < JN; j++) acc[i][j] = (f32x4){0.f, 0.f, 0.f, 0.f};

    // prologue: 2-deep prefetch
    stage_A(0, 0); stage_B(0, 0);
    stage_A(1, 1); stage_B(1, 1);

    const bf16 *Ab, *Bb;
    auto rdA = [&](int ii, int ge) -> bf16x8 {
        return *(const bf16x8*)&Ab[(arow + ii * 16) * 64 + ge];
    };
    auto rdB = [&](int jj, int ge) -> bf16x8 {
        return *(const bf16x8*)&Bb[(brow + jj * 16) * 64 + ge];
    };

    int p = 0;
    for (int kt = 0; kt < nt; ++kt) {
        // counted wait: tiles kt and kt+1 in flight (2*VMW); keep kt+1's flying.
        if (kt < nt - 1) {
            if constexpr (VMW == 8) asm volatile("s_waitcnt vmcnt(8)" ::: "memory");
            else                    asm volatile("s_waitcnt vmcnt(6)" ::: "memory");
        } else {
            asm volatile("s_waitcnt vmcnt(0)" ::: "memory");
        }
        BAR();                       // buf[p] globally ready
        Ab = sm + p * BUFE;
        Bb = Ab + BM * 64;

        bf16x8 a[IH][2], b[JH][2], b2[JH][2];

        // ---- phase 0: read A-half0 + B-half0; MFMA quadrant (0,0)
#pragma unroll
        for (int i = 0; i < IH; i++) { a[i][0] = rdA(i, g0e); a[i][1] = rdA(i, g1e); }
#pragma unroll
        for (int j = 0; j < JH; j++) { b[j][0] = rdB(j, g0e); b[j][1] = rdB(j, g1e); }
        BAR();
        WAIT_LGKM0();
        __builtin_amdgcn_s_setprio(1);
#pragma unroll
        for (int i = 0; i < IH; i++)
#pragma unroll
            for (int j = 0; j < JH; j++) {
                acc[i][j] = mfma16(a[i][0], b[j][0], acc[i][j]);
                acc[i][j] = mfma16(a[i][1], b[j][1], acc[i][j]);
            }
        __builtin_amdgcn_s_setprio(0);
        BAR();

        // ---- phase 1: read B-half1; MFMA quadrant (0,1)
#pragma unroll
        for (int j = 0; j < JH; j++) { b2[j][0] = rdB(JH + j, g0e); b2[j][1] = rdB(JH + j, g1e); }
        BAR();
        WAIT_LGKM0();
        __builtin_amdgcn_s_setprio(1);
#pragma unroll
        for (int i = 0; i < IH; i++)
#pragma unroll
            for (int j = 0; j < JH; j++) {
                acc[i][JH + j] = mfma16(a[i][0], b2[j][0], acc[i][JH + j]);
                acc[i][JH + j] = mfma16(a[i][1], b2[j][1], acc[i][JH + j]);
            }
        __builtin_amdgcn_s_setprio(0);
        BAR();

        // B region of buf[p] fully consumed by all waves -> refill for kt+2
        if (kt + 2 < nt) stage_B(kt + 2, p);

        // ---- phase 2: read A-half1 (reuse regs); MFMA quadrant (1,0)
#pragma unroll
        for (int i = 0; i < IH; i++) { a[i][0] = rdA(IH + i, g0e); a[i][1] = rdA(IH + i, g1e); }
        BAR();
        WAIT_LGKM0();
        __builtin_amdgcn_s_setprio(1);
#pragma unroll
        for (int i = 0; i < IH; i++)
#pragma unroll
            for (int j = 0; j < JH; j++) {
                acc[IH + i][j] = mfma16(a[i][0], b[j][0], acc[IH + i][j]);
                acc[IH + i][j] = mfma16(a[i][1], b[j][1], acc[IH + i][j]);
            }
        __builtin_amdgcn_s_setprio(0);
        BAR();

        // A region consumed -> refill for kt+2
        if (kt + 2 < nt) stage_A(kt + 2, p);

        // ---- phase 3: MFMA quadrant (1,1) (no reads; issues fly underneath)
        __builtin_amdgcn_s_setprio(1);
#pragma unroll
        for (int i = 0; i < IH; i++)
#pragma unroll
            for (int j = 0; j < JH; j++) {
                acc[IH + i][JH + j] = mfma16(a[i][0], b2[j][0], acc[IH + i][JH + j]);
                acc[IH + i][JH + j] = mfma16(a[i][1], b2[j][1], acc[IH + i][JH + j]);
            }
        __builtin_amdgcn_s_setprio(0);
        p ^= 1;
    }

    // =================== epilogues ===================
    if constexpr (MODE == 0) {
        const bool isq = (n0 < D_);
        bf16* oh = isq ? o_qh : o_kh;
        bf16* ol = isq ? o_ql : o_kl;
#pragma unroll
        for (int j = 0; j < JN; j++) {
            int nb = nsec + wc * (BN / WN) + j * 16;    // section-local n base
            int h = nb >> 7;
            float hv = hm[h];
#pragma unroll
            for (int i = 0; i < IM; i++) {
                int mB = m0 + wr * (BM / WM) + i * 16 + quad * 4;
                int bb = mB >> 11, s = mB & (S_ - 1);
                size_t idx0 = (((size_t)bb * H_ + h) * S_ + s) * HD_ + (nb & 127) + lrow;
#pragma unroll
                for (int r = 0; r < 4; r++) {
                    float v = acc[i][j][r] * hv;
                    bf16 hvv = (bf16)v;
                    bf16 lvv = (bf16)(v - (float)hvv);
                    oh[idx0 + (size_t)r * HD_] = hvv;
                    ol[idx0 + (size_t)r * HD_] = lvv;
                }
            }
        }
    }
    if constexpr (MODE == 1) {
        // LDS transpose in the (dead) staging buffers, then coalesced V^T write.
        __syncthreads();
        bf16* tr = sm;                       // [BN=256][136] (136 keeps 16B align)
#pragma unroll
        for (int j = 0; j < JN; j++) {
            int nl = wc * (BN / WN) + j * 16 + lrow;
            float hv = hm[(n0 + nl) >> 7];
#pragma unroll
            for (int i = 0; i < IM; i++) {
                int ml = wr * (BM / WM) + i * 16 + quad * 4;
                bf16x4 pk;
#pragma unroll
                for (int r = 0; r < 4; r++) pk[r] = (bf16)(acc[i][j][r] * hv);
                *(bf16x4*)&tr[nl * 136 + ml] = pk;
            }
        }
        __syncthreads();
        const int bI = m0 >> 11;
        const int s0 = m0 & (S_ - 1);
#pragma unroll
        for (int w = 0; w < 8; w++) {
            int nrow = w * 32 + (t >> 4);    // 0..255
            int c = t & 15;                  // 16 chunks of 8 along m (BM=128)
            bf16x8 vv = *(const bf16x8*)&tr[nrow * 136 + c * 8];
            int ng = n0 + nrow;
            int h = ng >> 7, hd = ng & 127;
            *(bf16x8*)&o_vt[((size_t)(bI * H_ + h) * HD_ + hd) * S_ + s0 + c * 8] = vv;
        }
    }
    if constexpr (MODE == 2) {
#pragma unroll
        for (int j = 0; j < JN; j++) {
            int n = n0 + wc * (BN / WN) + j * 16 + lrow;
#pragma unroll
            for (int i = 0; i < IM; i++) {
                int mB = m0 + wr * (BM / WM) + i * 16 + quad * 4;
#pragma unroll
                for (int r = 0; r < 4; r++)
                    o_f32[(size_t)(mB + r) * D_ + n] = acc[i][j][r];
            }
        }
    }
}

// =================== causal flash attention (MFMA, split QK) ===================
// unchanged from previous round (all LDS staging via global_load_lds + XOR swizzle)
#define SPLD 72

__global__ __launch_bounds__(256, 2)
void attn_kernel(const bf16* __restrict__ qh_, const bf16* __restrict__ ql_,
                 const bf16* __restrict__ kh_, const bf16* __restrict__ kl_,
                 const bf16* __restrict__ vt_, const float* __restrict__ am,
                 bf16* __restrict__ outp) {
    const int bh = blockIdx.x & 31;
    const int qblk = 31 - (blockIdx.x >> 5);
    const int b = bh >> 4, h = bh & 15;
    const int i0 = qblk * 64;
    const int t = threadIdx.x, wave = t >> 6, lane = t & 63;
    const int lrow = lane & 15, quad = lane >> 4;

    __shared__ bf16 skh[64 * 128];                 // swizzled [j][d]
    __shared__ bf16 skl[64 * 128];
    __shared__ bf16 svt[128 * 64];                 // swizzled [d][j]
    __shared__ bf16 sp[4][16 * SPLD];              // per-wave P strip (padded)

    const size_t kbase = (size_t)bh * S_ * HD_;
    const size_t vbase = (size_t)bh * HD_ * S_;

    const int qrow = i0 + wave * 16 + lrow;
    bf16x8 qhf[4], qlf[4];
#pragma unroll
    for (int c = 0; c < 4; c++) {
        qhf[c] = *(const bf16x8*)&qh_[kbase + (size_t)qrow * HD_ + c * 32 + quad * 8];
        qlf[c] = *(const bf16x8*)&ql_[kbase + (size_t)qrow * HD_ + c * 32 + quad * 8];
    }

    float m_i[4], l_i[4];
    f32x4 O[8];
#pragma unroll
    for (int r = 0; r < 4; r++) { m_i[r] = -INFINITY; l_i[r] = 0.f; }
#pragma unroll
    for (int n2 = 0; n2 < 8; n2++) O[n2] = (f32x4){0.f, 0.f, 0.f, 0.f};

    const float scale = 0.08838834764831845f;  // 1/sqrt(128)

    for (int j0 = 0; j0 <= i0; j0 += 64) {
        __syncthreads();
#pragma unroll
        for (int p = 0; p < 4; p++) {
            int rb = wave * 16 + p * 4;
            int r = rb + (lane >> 4);
            int gl = ((lane & 15) ^ (r & 7)) * 8;
            gld_lds16(kh_ + kbase + (size_t)(j0 + r) * HD_ + gl, &skh[rb * 128]);
            gld_lds16(kl_ + kbase + (size_t)(j0 + r) * HD_ + gl, &skl[rb * 128]);
        }
#pragma unroll
        for (int p = 0; p < 4; p++) {
            int db = wave * 32 + p * 8;
            int d = db + (lane >> 3);
            int gl = ((lane & 7) ^ (d & 7)) * 8;
            gld_lds16(vt_ + vbase + (size_t)d * S_ + j0 + gl, &svt[db * 64]);
        }
        __syncthreads();

        float amadd[4];
#pragma unroll
        for (int nt = 0; nt < 4; nt++)
            amadd[nt] = (1.0f - am[b * S_ + j0 + nt * 16 + lrow]) * -10000.0f;

        f32x4 s4[4];
#pragma unroll
        for (int nt = 0; nt < 4; nt++) s4[nt] = (f32x4){0.f, 0.f, 0.f, 0.f};
#pragma unroll
        for (int c = 0; c < 4; c++) {
#pragma unroll
            for (int nt = 0; nt < 4; nt++) {
                int ka = (nt * 16 + lrow) * 128 + (((c * 4 + quad) ^ (lrow & 7)) * 8);
                bf16x8 kb8 = *(const bf16x8*)&skh[ka];
                bf16x8 lb8 = *(const bf16x8*)&skl[ka];
                s4[nt] = __builtin_amdgcn_mfma_f32_16x16x32_bf16(qhf[c], kb8, s4[nt], 0, 0, 0);
                s4[nt] = __builtin_amdgcn_mfma_f32_16x16x32_bf16(qhf[c], lb8, s4[nt], 0, 0, 0);
                s4[nt] = __builtin_amdgcn_mfma_f32_16x16x32_bf16(qlf[c], kb8, s4[nt], 0, 0, 0);
            }
        }

        const bool diag = (j0 == i0);
#pragma unroll
        for (int r = 0; r < 4; r++) {
            const int rrow = wave * 16 + quad * 4 + r;
            float sv[4], pw[4];
            float mx = -INFINITY;
#pragma unroll
            for (int nt = 0; nt < 4; nt++) {
                float xv = s4[nt][r] * scale + amadd[nt];
                if (diag && (nt * 16 + lrow) > rrow) xv = -INFINITY;
                sv[nt] = xv;
                mx = fmaxf(mx, xv);
            }
#pragma unroll
            for (int off = 1; off < 16; off <<= 1) mx = fmaxf(mx, __shfl_xor(mx, off));
            float mnew = fmaxf(m_i[r], mx);
            float alpha = __expf(m_i[r] - mnew);
            float ps = 0.f;
#pragma unroll
            for (int nt = 0; nt < 4; nt++) { pw[nt] = __expf(sv[nt] - mnew); ps += pw[nt]; }
#pragma unroll
            for (int off = 1; off < 16; off <<= 1) ps += __shfl_xor(ps, off);
            l_i[r] = l_i[r] * alpha + ps;
            m_i[r] = mnew;
#pragma unroll
            for (int n2 = 0; n2 < 8; n2++) O[n2][r] *= alpha;
#pragma unroll
            for (int nt = 0; nt < 4; nt++)
                sp[wave][(quad * 4 + r) * SPLD + nt * 16 + lrow] = (bf16)pw[nt];
        }
        __asm__ volatile("s_waitcnt lgkmcnt(0)" ::: "memory");   // sp per-wave

#pragma unroll
        for (int k2 = 0; k2 < 2; k2++) {
            bf16x8 pf = *(const bf16x8*)&sp[wave][lrow * SPLD + k2 * 32 + quad * 8];
            const int gp = ((quad + k2 * 4) ^ (lrow & 7)) * 8;
#pragma unroll
            for (int n2 = 0; n2 < 8; n2++) {
                bf16x8 vf8 = *(const bf16x8*)&svt[(n2 * 16 + lrow) * 64 + gp];
                O[n2] = __builtin_amdgcn_mfma_f32_16x16x32_bf16(pf, vf8, O[n2], 0, 0, 0);
            }
        }
    }

    float inv[4];
#pragma unroll
    for (int r = 0; r < 4; r++) inv[r] = 1.0f / l_i[r];
#pragma unroll
    for (int n2 = 0; n2 < 8; n2++)
#pragma unroll
        for (int r = 0; r < 4; r++) {
            int srow = i0 + wave * 16 + quad * 4 + r;
            outp[((size_t)(b * S_ + srow)) * D_ + h * HD_ + n2 * 16 + lrow] =
                (bf16)(O[n2][r] * inv[r]);
        }
}

// =================== launch ===================
extern "C" void kernel_launch(void* const* d_in, const int* in_sizes, int n_in,
                              void* d_out, int out_size, void* d_ws, size_t ws_size,
                              hipStream_t stream) {
    const float* x  = (const float*)d_in[0];
    const float* qm = (const float*)d_in[1];
    const float* km = (const float*)d_in[2];
    const float* vm = (const float*)d_in[3];
    const float* om = (const float*)d_in[4];
    const float* hm = (const float*)d_in[5];
    const float* am = (const float*)d_in[6];
    const float* sw = (const float*)d_in[7];
    float* out = (float*)d_out;

    // ws (96 MiB): [xh | xl | qh | ql | kh | kl].
    //   vmb (v-mask bf16) reuses xl AFTER the q/k gemm (v gemm uses xh only).
    //   attn_out reuses xh after gemm0; omb reuses qh after attn.
    // d_out (32 MiB) scratch: vt at +0 (16M), qmb at +16M (8M), kmb at +24M (8M);
    //   all dead before the output-projection gemm writes out.
    const size_t P = (size_t)B_ * H_ * S_ * HD_ * sizeof(bf16);   // 16 MiB
    char* ws = (char*)d_ws;
    bf16* xh = (bf16*)(ws + 0 * P);
    bf16* xl = (bf16*)(ws + 1 * P);
    bf16* qh = (bf16*)(ws + 2 * P);
    bf16* ql = (bf16*)(ws + 3 * P);
    bf16* kh = (bf16*)(ws + 4 * P);
    bf16* kl = (bf16*)(ws + 5 * P);
    bf16* attn_out = xh;
    bf16* vmb = xl;
    bf16* omb = qh;
    bf16* vt  = (bf16*)d_out;
    bf16* qmb = (bf16*)((char*)d_out + 16u * 1024 * 1024);
    bf16* kmb = (bf16*)((char*)d_out + 24u * 1024 * 1024);

    precast_kernel<<<(B_ * S_ * D_) / (256 * 8), 256, 0, stream>>>(x, xh, xl);
    precast_mask<<<4096, 256, 0, stream>>>(qm, qmb, km, kmb, sw);

    // q/k projection: 256x256 tiles, virtual K=4096 (hi|lo), 256 blocks = 1 round
    gemm8p<256, 256, 2, 4, 0><<<dim3(16, 16), 512, 0, stream>>>(
        xh, xl, qmb, kmb, hm, qh, ql, kh, kl, nullptr, nullptr, 64);

    // v mask precast into (now free) xl slot, then v projection (hi only),
    // 128x256 tiles, 256 blocks = 1 round; writes V^T directly.
    precast_mask<<<2048, 256, 0, stream>>>(vm, vmb, nullptr, nullptr, sw);
    gemm8p<128, 256, 2, 4, 1><<<dim3(8, 32), 512, 0, stream>>>(
        xh, nullptr, vmb, nullptr, hm,
        nullptr, nullptr, nullptr, nullptr, vt, nullptr, 32);

    // attention: 1024 blocks (32 qblk x 32 bh), reversed qblk for backfill
    attn_kernel<<<1024, 256, 0, stream>>>(qh, ql, kh, kl, vt, am, attn_out);

    // output projection: 256x128 tiles, 256 blocks = 1 round, f32 out
    precast_mask<<<2048, 256, 0, stream>>>(om, omb, nullptr, nullptr, sw);
    gemm8p<256, 128, 4, 2, 2><<<dim3(16, 16), 512, 0, stream>>>(
        attn_out, nullptr, omb, nullptr, hm,
        nullptr, nullptr, nullptr, nullptr, nullptr, out, 32);
}